// Round 7
// baseline (61.323 us; speedup 1.0000x reference)
//
#include <hip/hip_runtime.h>
#include <math.h>

#define NN 4096
#define ROWS 16

typedef float fvec4 __attribute__((ext_vector_type(4)));

// out[b,u,v] = -sgn(u-v) * p[b,u] * p[b,v] * sin(2(u-v))   (Re of the
// complex64 ref; harness casts .astype(float32))
//   p[b,x] = sqrt(0.5) * sqrt(|V[b,x]| + 1e-10) / (1 + x)
//
// Identity used: p_v * sin(2(u-v)) = su*cp[v] - cu*sp[v]
//   with cp[v] = p_v*cos(2v), sp[v] = p_v*sin(2v)  (packed LDS tables, 32 KB
//   total -> 4 blocks/CU resident = exactly grid/CU -> no residency tail).
//
// One block per 16 consecutive u-rows (16 | 4096, no b-straddle).
// Inner loop: 2x ds_read_b128 -> 4 outputs -> 1 float4 nontemporal store.
__global__ __launch_bounds__(256) void bs_main(const float* __restrict__ V,
                                               int nV,
                                               float* __restrict__ out,
                                               long long out_floats) {
    __shared__ float chi[64], shi[64], clo[64], slo[64];
    __shared__ float cp[NN];   // p_v * cos(2v)
    __shared__ float sp[NN];   // p_v * sin(2v)

    const int t = threadIdx.x;
    const int row0 = blockIdx.x * ROWS;
    const int b = row0 >> 12;                 // N == 4096

    if (t < 64) {
        double a = 128.0 * (double)t;         // 2 * (64*t)
        chi[t] = (float)cos(a);
        shi[t] = (float)sin(a);
    } else if (t < 128) {
        const int k = t - 64;
        double a = 2.0 * (double)k;
        clo[k] = (float)cos(a);
        slo[k] = (float)sin(a);
    }
    __syncthreads();                          // hi/lo tables ready

    const int vbase = b << 12;
    for (int i = t; i < NN; i += 256) {
        const int gi = vbase + i;
        const float v = (gi < nV) ? V[gi] : 0.0f;
        const float p = 0.70710678118654752f * sqrtf(fabsf(v) + 1e-10f)
                        / (1.0f + (float)i);
        const int h = i >> 6, l = i & 63;
        const float c = chi[h] * clo[l] - shi[h] * slo[l];   // cos(2i)
        const float s = shi[h] * clo[l] + chi[h] * slo[l];   // sin(2i)
        cp[i] = p * c;
        sp[i] = p * s;
    }
    __syncthreads();

    for (int r = 0; r < ROWS; ++r) {
        const int row = row0 + r;
        const int u = row & (NN - 1);

        const int uh = u >> 6, ul = u & 63;
        const float cu = chi[uh] * clo[ul] - shi[uh] * slo[ul];  // cos(2u)
        const float su = shi[uh] * clo[ul] + chi[uh] * slo[ul];  // sin(2u)

        const int gu = vbase + u;
        const float vu = (gu < nV) ? V[gu] : 0.0f;               // broadcast
        const float pu = 0.70710678118654752f * sqrtf(fabsf(vu) + 1e-10f)
                         / (1.0f + (float)u);

        const long long rowbase = (long long)row * NN;

        for (int j = t; j < NN / 4; j += 256) {
            const int v0 = 4 * j;
            const fvec4 cp4 = *(const fvec4*)&cp[v0];   // ds_read_b128
            const fvec4 sp4 = *(const fvec4*)&sp[v0];

            fvec4 o;
            #pragma unroll
            for (int k = 0; k < 4; ++k) {
                const int v = v0 + k;
                const float m = pu * (su * cp4[k] - cu * sp4[k]);
                o[k] = (u > v) ? -m : ((u < v) ? m : 0.0f);  // -sgn(u-v)*m
            }

            const long long base = rowbase + v0;
            if (base + 4 <= out_floats) {
                __builtin_nontemporal_store(o, (fvec4*)(out + base));
            }
        }
    }
}

extern "C" void kernel_launch(void* const* d_in, const int* in_sizes, int n_in,
                              void* d_out, int out_size, void* d_ws, size_t ws_size,
                              hipStream_t stream) {
    const float* V = (const float*)d_in[0];
    const int nV = in_sizes[0];                       // B*N = 16384 expected

    long long out_floats = (long long)out_size;       // one float per (b,u,v)
    long long rows_ll = out_floats / NN;
    if (rows_ll <= 0) return;
    int grid = (int)((rows_ll + ROWS - 1) / ROWS);

    bs_main<<<grid, 256, 0, stream>>>(V, nV, (float*)d_out, out_floats);
}

// Round 8
// 52.775 us; speedup vs baseline: 1.1620x; 1.1620x over previous
//
#include <hip/hip_runtime.h>
#include <math.h>

#define NN 4096
#define ROWS 16

typedef float fvec4 __attribute__((ext_vector_type(4)));

// out[b,u,v] = -sgn(u-v) * p[b,u] * p[b,v] * sin(2(u-v))   (Re of the
// complex64 ref; harness casts .astype(float32))
//   p[b,x] = sqrt(0.5) * sqrt(|V[b,x]| + 1e-10) / (1 + x)
//
// Identity: p_v * sin(2(u-v)) = su*cp[v] - cu*sp[v],
//   cp[v] = p_v*cos(2v), sp[v] = p_v*sin(2v)  (32 KB packed LDS tables).
//
// One block per 16 consecutive u-rows (16 | 4096, no b-straddle).
// R8 changes vs R7: PLAIN stores (no nontemporal hint) + per-row hoisted
// bounds guard (row < nrows => entire row in-bounds), so the inner loop is
// branch-free: 2x ds_read_b128 -> 4 outputs -> 1 global_store_dwordx4.
__global__ __launch_bounds__(256) void bs_main(const float* __restrict__ V,
                                               int nV,
                                               float* __restrict__ out,
                                               int nrows) {
    __shared__ float chi[64], shi[64], clo[64], slo[64];
    __shared__ float cp[NN];   // p_v * cos(2v)
    __shared__ float sp[NN];   // p_v * sin(2v)

    const int t = threadIdx.x;
    const int row0 = blockIdx.x * ROWS;
    const int b = row0 >> 12;                 // N == 4096

    if (t < 64) {
        double a = 128.0 * (double)t;         // 2 * (64*t)
        chi[t] = (float)cos(a);
        shi[t] = (float)sin(a);
    } else if (t < 128) {
        const int k = t - 64;
        double a = 2.0 * (double)k;
        clo[k] = (float)cos(a);
        slo[k] = (float)sin(a);
    }
    __syncthreads();                          // hi/lo tables ready

    const int vbase = b << 12;
    for (int i = t; i < NN; i += 256) {
        const int gi = vbase + i;
        const float v = (gi < nV) ? V[gi] : 0.0f;
        const float p = 0.70710678118654752f * sqrtf(fabsf(v) + 1e-10f)
                        / (1.0f + (float)i);
        const int h = i >> 6, l = i & 63;
        const float c = chi[h] * clo[l] - shi[h] * slo[l];   // cos(2i)
        const float s = shi[h] * clo[l] + chi[h] * slo[l];   // sin(2i)
        cp[i] = p * c;
        sp[i] = p * s;
    }
    __syncthreads();

    for (int r = 0; r < ROWS; ++r) {
        const int row = row0 + r;
        if (row >= nrows) return;             // nrows = out_floats/NN (floor)
        const int u = row & (NN - 1);

        const int uh = u >> 6, ul = u & 63;
        const float cu = chi[uh] * clo[ul] - shi[uh] * slo[ul];  // cos(2u)
        const float su = shi[uh] * clo[ul] + chi[uh] * slo[ul];  // sin(2u)

        const int gu = vbase + u;
        const float vu = (gu < nV) ? V[gu] : 0.0f;               // broadcast
        const float pu = 0.70710678118654752f * sqrtf(fabsf(vu) + 1e-10f)
                         / (1.0f + (float)u);

        float* __restrict__ orow = out + (size_t)row * NN;

        #pragma unroll
        for (int j = t; j < NN / 4; j += 256) {   // exactly 4 iterations
            const int v0 = 4 * j;
            const fvec4 cp4 = *(const fvec4*)&cp[v0];   // ds_read_b128
            const fvec4 sp4 = *(const fvec4*)&sp[v0];

            fvec4 o;
            #pragma unroll
            for (int k = 0; k < 4; ++k) {
                const int v = v0 + k;
                const float m = pu * (su * cp4[k] - cu * sp4[k]);
                o[k] = (u > v) ? -m : ((u < v) ? m : 0.0f);  // -sgn(u-v)*m
            }

            *(fvec4*)(orow + v0) = o;         // plain coalesced 16B store
        }
    }
}

extern "C" void kernel_launch(void* const* d_in, const int* in_sizes, int n_in,
                              void* d_out, int out_size, void* d_ws, size_t ws_size,
                              hipStream_t stream) {
    const float* V = (const float*)d_in[0];
    const int nV = in_sizes[0];                       // B*N = 16384 expected

    long long out_floats = (long long)out_size;       // one float per (b,u,v)
    long long nrows = out_floats / NN;                // full rows only
    if (nrows <= 0) return;
    int grid = (int)((nrows + ROWS - 1) / ROWS);

    bs_main<<<grid, 256, 0, stream>>>(V, nV, (float*)d_out, (int)nrows);
}

// Round 9
// 51.619 us; speedup vs baseline: 1.1880x; 1.0224x over previous
//
#include <hip/hip_runtime.h>
#include <math.h>

#define NN 4096
#define ROWS 16

typedef float fvec4 __attribute__((ext_vector_type(4)));

// out[b,u,v] = -sgn(u-v) * p[b,u] * p[b,v] * sin(2(u-v))   (Re of complex64
// ref; harness stores .astype(float32))
//   p[b,x] = sqrt(0.5) * sqrt(|V[b,x]| + 1e-10) / (1 + x)
// Identity: p_v*sin(2(u-v)) = su*cp[v] - cu*sp[v],
//   cp[v]=p_v*cos(2v), sp[v]=p_v*sin(2v).

// Kernel 1: exact-f64 table precompute into d_ws (cp|sp per batch, 2*NN each).
__global__ __launch_bounds__(256) void bs_tables(const float* __restrict__ V,
                                                 int nV,
                                                 float* __restrict__ ws) {
    const int i = blockIdx.x * 256 + threadIdx.x;    // i = b*NN + v
    if (i >= nV) return;
    const int b = i >> 12, v = i & (NN - 1);
    const float val = V[i];
    const float p = 0.70710678118654752f * sqrtf(fabsf(val) + 1e-10f)
                    / (1.0f + (float)v);
    const double a = 2.0 * (double)v;
    float* wb = ws + (size_t)b * (2 * NN);
    wb[v]      = p * (float)cos(a);
    wb[NN + v] = p * (float)sin(a);
}

// Kernel 2: stream kernel. Setup = 32 KB global->LDS copy + 16 row-scalars;
// steady state = 2x ds_read_b128 + ~12 VALU + 1 dwordx4 store per 4 outputs.
// use_ws==0 fallback builds tables in-LDS (f64 trig) if ws was too small.
__global__ __launch_bounds__(256) void bs_main(const float* __restrict__ V,
                                               int nV,
                                               const float* __restrict__ ws,
                                               int use_ws,
                                               float* __restrict__ out,
                                               int nrows) {
    __shared__ float tab[2 * NN];          // cp = tab[0..NN), sp = tab[NN..2NN)
    __shared__ float rs_c[ROWS], rs_s[ROWS];   // cu*pu, su*pu per row

    const int t = threadIdx.x;
    const int row0 = blockIdx.x * ROWS;
    const int b = row0 >> 12;              // N == 4096
    const int vbase = b << 12;

    if (use_ws) {
        // stage precomputed tables: 2048 float4s, 8 per thread
        const fvec4* __restrict__ src = (const fvec4*)(ws + (size_t)b * (2 * NN));
        fvec4* __restrict__ dst = (fvec4*)tab;
        #pragma unroll
        for (int j = t; j < (2 * NN) / 4; j += 256) dst[j] = src[j];
    } else {
        for (int i = t; i < NN; i += 256) {
            const int gi = vbase + i;
            const float val = (gi < nV) ? V[gi] : 0.0f;
            const float p = 0.70710678118654752f * sqrtf(fabsf(val) + 1e-10f)
                            / (1.0f + (float)i);
            const double a = 2.0 * (double)i;
            tab[i]      = p * (float)cos(a);
            tab[NN + i] = p * (float)sin(a);
        }
    }

    if (t < ROWS) {                        // per-row scalars, one wave, parallel
        const int u = (row0 + t) & (NN - 1);
        const int gu = vbase + u;
        const float vu = (gu < nV) ? V[gu] : 0.0f;
        const float pu = 0.70710678118654752f * sqrtf(fabsf(vu) + 1e-10f)
                         / (1.0f + (float)u);
        const double a = 2.0 * (double)u;
        rs_c[t] = pu * (float)cos(a);
        rs_s[t] = pu * (float)sin(a);
    }
    __syncthreads();

    for (int r = 0; r < ROWS; ++r) {
        const int row = row0 + r;
        if (row >= nrows) return;          // nrows = out_size/NN (full rows)
        const int u = row & (NN - 1);
        const float cuP = rs_c[r];         // pu*cos(2u)
        const float suP = rs_s[r];         // pu*sin(2u)
        float* __restrict__ orow = out + (size_t)row * NN;

        #pragma unroll
        for (int j = t; j < NN / 4; j += 256) {   // exactly 4 iterations
            const int v0 = 4 * j;
            const fvec4 cp4 = *(const fvec4*)&tab[v0];        // ds_read_b128
            const fvec4 sp4 = *(const fvec4*)&tab[NN + v0];   // ds_read_b128

            fvec4 o;
            #pragma unroll
            for (int k = 0; k < 4; ++k) {
                const int v = v0 + k;
                const float m = suP * cp4[k] - cuP * sp4[k];  // pu*pv*sin(2(u-v))
                o[k] = (u > v) ? -m : ((u < v) ? m : 0.0f);   // -sgn(u-v)*m
            }
            *(fvec4*)(orow + v0) = o;      // plain coalesced 16B store
        }
    }
}

extern "C" void kernel_launch(void* const* d_in, const int* in_sizes, int n_in,
                              void* d_out, int out_size, void* d_ws, size_t ws_size,
                              hipStream_t stream) {
    const float* V = (const float*)d_in[0];
    const int nV = in_sizes[0];                       // B*N = 16384 expected

    long long nrows = (long long)out_size / NN;       // one float per (b,u,v)
    if (nrows <= 0) return;
    const int grid = (int)((nrows + ROWS - 1) / ROWS);

    const size_t ws_needed = (size_t)((nV + NN - 1) / NN) * (2 * NN) * sizeof(float);
    const int use_ws = (d_ws != nullptr && ws_size >= ws_needed) ? 1 : 0;

    if (use_ws) {
        bs_tables<<<(nV + 255) / 256, 256, 0, stream>>>(V, nV, (float*)d_ws);
    }
    bs_main<<<grid, 256, 0, stream>>>(V, nV, (const float*)d_ws, use_ws,
                                      (float*)d_out, (int)nrows);
}

// Round 10
// 50.803 us; speedup vs baseline: 1.2071x; 1.0161x over previous
//
#include <hip/hip_runtime.h>
#include <math.h>

#define NN 4096
#define ROWS 16
#define HALF 8

typedef float fvec4 __attribute__((ext_vector_type(4)));

// out[b,u,v] = -sgn(u-v) * p[b,u] * p[b,v] * sin(2(u-v))   (Re of complex64
// ref; harness stores .astype(float32))
//   p[b,x] = sqrt(0.5) * sqrt(|V[b,x]| + 1e-10) / (1 + x)
// Identity: p_v*sin(2(u-v)) = su*cp[v] - cu*sp[v],
//   cp[v]=p_v*cos(2v), sp[v]=p_v*sin(2v).

// Kernel 1: exact-f64 table precompute into d_ws (cp|sp per batch, 2*NN each).
__global__ __launch_bounds__(256) void bs_tables(const float* __restrict__ V,
                                                 int nV,
                                                 float* __restrict__ ws) {
    const int i = blockIdx.x * 256 + threadIdx.x;    // i = b*NN + v
    if (i >= nV) return;
    const int b = i >> 12, v = i & (NN - 1);
    const float val = V[i];
    const float p = 0.70710678118654752f * sqrtf(fabsf(val) + 1e-10f)
                    / (1.0f + (float)v);
    const double a = 2.0 * (double)v;
    float* wb = ws + (size_t)b * (2 * NN);
    wb[v]      = p * (float)cos(a);
    wb[NN + v] = p * (float)sin(a);
}

// Kernel 2: stream kernel with ROW-PAIRING: each inner iteration reads the
// v-tables once and emits stores for TWO rows (r, r+8) -> 32 B/lane/iter,
// doubled store MLP, halved LDS traffic per byte written.
__global__ __launch_bounds__(256) void bs_main(const float* __restrict__ V,
                                               int nV,
                                               const float* __restrict__ ws,
                                               int use_ws,
                                               float* __restrict__ out,
                                               int nrows) {
    __shared__ float tab[2 * NN];          // cp = tab[0..NN), sp = tab[NN..2NN)
    __shared__ float rs_c[ROWS], rs_s[ROWS];   // pu*cos(2u), pu*sin(2u)

    const int t = threadIdx.x;
    const int row0 = blockIdx.x * ROWS;
    const int b = row0 >> 12;              // N == 4096
    const int vbase = b << 12;

    if (use_ws) {
        const fvec4* __restrict__ src = (const fvec4*)(ws + (size_t)b * (2 * NN));
        fvec4* __restrict__ dst = (fvec4*)tab;
        #pragma unroll
        for (int j = t; j < (2 * NN) / 4; j += 256) dst[j] = src[j];
    } else {                               // fallback: build tables in-kernel
        for (int i = t; i < NN; i += 256) {
            const int gi = vbase + i;
            const float val = (gi < nV) ? V[gi] : 0.0f;
            const float p = 0.70710678118654752f * sqrtf(fabsf(val) + 1e-10f)
                            / (1.0f + (float)i);
            const double a = 2.0 * (double)i;
            tab[i]      = p * (float)cos(a);
            tab[NN + i] = p * (float)sin(a);
        }
    }

    if (t < ROWS) {                        // per-row scalars, parallel
        const int u = (row0 + t) & (NN - 1);
        const int gu = vbase + u;
        const float vu = (gu < nV) ? V[gu] : 0.0f;
        const float pu = 0.70710678118654752f * sqrtf(fabsf(vu) + 1e-10f)
                         / (1.0f + (float)u);
        const double a = 2.0 * (double)u;
        rs_c[t] = pu * (float)cos(a);
        rs_s[t] = pu * (float)sin(a);
    }
    __syncthreads();

    for (int r = 0; r < HALF; ++r) {
        const int rowA = row0 + r;
        const int rowB = rowA + HALF;
        if (rowA >= nrows) return;
        const bool hasB = (rowB < nrows);

        const int uA = rowA & (NN - 1);
        const int uB = rowB & (NN - 1);
        const float cA = rs_c[r],        sA = rs_s[r];
        const float cB = rs_c[r + HALF], sB = rs_s[r + HALF];

        float* __restrict__ orowA = out + (size_t)rowA * NN;
        float* __restrict__ orowB = out + (size_t)rowB * NN;

        #pragma unroll
        for (int j = t; j < NN / 4; j += 256) {   // exactly 4 iterations
            const int v0 = 4 * j;
            const fvec4 cp4 = *(const fvec4*)&tab[v0];        // ds_read_b128
            const fvec4 sp4 = *(const fvec4*)&tab[NN + v0];   // ds_read_b128

            fvec4 oA, oB;
            #pragma unroll
            for (int k = 0; k < 4; ++k) {
                const int v = v0 + k;
                const float mA = sA * cp4[k] - cA * sp4[k];   // puA*pv*sin(2(uA-v))
                const float mB = sB * cp4[k] - cB * sp4[k];
                oA[k] = (uA > v) ? -mA : ((uA < v) ? mA : 0.0f);
                oB[k] = (uB > v) ? -mB : ((uB < v) ? mB : 0.0f);
            }

            *(fvec4*)(orowA + v0) = oA;    // 2 coalesced 16B stores / iter
            if (hasB) *(fvec4*)(orowB + v0) = oB;
        }
    }
}

extern "C" void kernel_launch(void* const* d_in, const int* in_sizes, int n_in,
                              void* d_out, int out_size, void* d_ws, size_t ws_size,
                              hipStream_t stream) {
    const float* V = (const float*)d_in[0];
    const int nV = in_sizes[0];                       // B*N = 16384 expected

    long long nrows = (long long)out_size / NN;       // one float per (b,u,v)
    if (nrows <= 0) return;
    const int grid = (int)((nrows + ROWS - 1) / ROWS);

    const size_t ws_needed = (size_t)((nV + NN - 1) / NN) * (2 * NN) * sizeof(float);
    const int use_ws = (d_ws != nullptr && ws_size >= ws_needed) ? 1 : 0;

    if (use_ws) {
        bs_tables<<<(nV + 255) / 256, 256, 0, stream>>>(V, nV, (float*)d_ws);
    }
    bs_main<<<grid, 256, 0, stream>>>(V, nV, (const float*)d_ws, use_ws,
                                      (float*)d_out, (int)nrows);
}